// Round 14
// baseline (27.123 us; speedup 1.0000x reference)
//
#include <hip/hip_runtime.h>

// CTC batch cost, B=256 T=512 C=256 L=64 (S=129).
// R14 = R13 (reg-staging producers: global_load_dwordx4 -> VGPR ->
// ds_write_b128; wid0=fwd DP, wid1=bwd DP, wid2..5 = 4 producers) with the
// 32 s_barrier rendezvous replaced by LDS FLAG handshakes: producers
// free-run up to 8 groups ahead (ring = 8 groups x 8 rows per dir, 128 KB),
// consumers spin on per-slot flags. R13 lesson: depth, consumer latency,
// producer count, barrier count, and DMA-vs-reg path are all ~flat at
// ~5 TB/s -> last hypothesis is the lockstep cadence itself (any straggler
// stalls all 6 waves). Ordering: per-wave DS in-order + lgkmcnt(0) before
// each flag write => flag visible implies data visible; ring guard
// cdone >= g-8 prevents WAR. DP math: f64 linear domain, DPP wave shifts,
// log2-domain cut combine (absmax 0.0 in R6-R13).

constexpr int Bc = 256;
constexpr int Tc = 512;
constexpr int Cc = 256;
constexpr int Lc = 64;
constexpr int NG = 8;           // ring groups per direction (8 rows each)

#define EPSF (1e-7f)
#define NEGF (-1e30f)

__device__ __forceinline__ float flog2(float x) {
    float r; asm("v_log_f32 %0, %1" : "=v"(r) : "v"(x)); return r;
}
__device__ __forceinline__ float fexp2(float x) {
    float r; asm("v_exp_f32 %0, %1" : "=v"(r) : "v"(x)); return r;
}
__device__ __forceinline__ float lse2(float a, float b) {
    float m = fmaxf(a, b);
    float d = fminf(a, b) - m;
    return m + flog2(1.f + fexp2(d));
}
// log2 of a positive double via exponent extraction + f32 mantissa log.
__device__ __forceinline__ float dlog2(double x) {
    if (!(x > 1e-300)) return NEGF;
    const int hb = __double2hiint(x);
    const int lb = __double2loint(x);
    const int e  = ((hb >> 20) & 0x7FF) - 1022;
    const double m = __hiloint2double((hb & 0x800FFFFF) | (1022 << 20), lb);
    return flog2((float)m) + (float)e;            // m in [0.5, 1)
}
// double wave shifts via paired 32-bit DPP; 'old' fills the boundary lane.
__device__ __forceinline__ double dpp_up1_d(double old, double src) {   // lane i <- i-1
    const int rl = __builtin_amdgcn_update_dpp(
        __double2loint(old), __double2loint(src), 0x138, 0xF, 0xF, false);
    const int rh = __builtin_amdgcn_update_dpp(
        __double2hiint(old), __double2hiint(src), 0x138, 0xF, 0xF, false);
    return __hiloint2double(rh, rl);
}
__device__ __forceinline__ double dpp_dn1_d(double old, double src) {   // lane i <- i+1
    const int rl = __builtin_amdgcn_update_dpp(
        __double2loint(old), __double2loint(src), 0x130, 0xF, 0xF, false);
    const int rh = __builtin_amdgcn_update_dpp(
        __double2hiint(old), __double2hiint(src), 0x130, 0xF, 0xF, false);
    return __hiloint2double(rh, rl);
}

__global__ __launch_bounds__(384, 1) void ctc_fb_kernel(
        const int* __restrict__ y_true,
        const float* __restrict__ y_pred,
        float* __restrict__ out)
{
    const int b    = blockIdx.x;
    const int lane = threadIdx.x & 63;
    const int wid  = threadIdx.x >> 6;

    __shared__ float ring[2][NG * 8][Cc];          // 128 KB
    __shared__ volatile int pflag[2][2][NG];       // [dir][half][slotgrp] = g
    __shared__ volatile int cdone[2];              // [dir] = last consumed g
    __shared__ float Cl[64], Ch[64];
    __shared__ float CexS;

    // init flags, then the only pre-loop barrier
    if (threadIdx.x < 32)
        pflag[threadIdx.x >> 4][(threadIdx.x >> 3) & 1][threadIdx.x & 7] = -1;
    if (threadIdx.x == 32) cdone[0] = -1;
    if (threadIdx.x == 33) cdone[1] = -1;
    __syncthreads();

    const float* __restrict__ bbase = y_pred + (size_t)b * Tc * Cc;

    double lo = 0.0, hi = 0.0, ex = 0.0;

    if (wid >= 2) {
        // ------------- producer waves: wid-2 = {fwd0, bwd0, fwd1, bwd1} ----
        const int pid  = wid - 2;
        const int dir  = pid & 1;
        const int half = pid >> 1;           // which 4-row half of each group
        const float* __restrict__ g0 =
            dir ? (bbase + (size_t)(Tc - 1) * Cc + lane * 4)
                : (bbase + lane * 4);
        const ptrdiff_t stp = dir ? -(ptrdiff_t)Cc : (ptrdiff_t)Cc;

        float4 a0, a1, a2, a3, b0, b1, b2, b3;   // two named reg sets

#define GADDR(G, j) (g0 + stp * (8 * (G) + 4 * half + (j)))
#define LADDR(G, j) (&ring[dir][((G) & 7) * 8 + 4 * half + (j)][lane * 4])
#define PLOAD(v0, v1, v2, v3, G)                                   \
        v0 = *(const float4*)GADDR(G, 0);                          \
        v1 = *(const float4*)GADDR(G, 1);                          \
        v2 = *(const float4*)GADDR(G, 2);                          \
        v3 = *(const float4*)GADDR(G, 3);
#define PWRITE(v0, v1, v2, v3, G)                                  \
        *(float4*)LADDR(G, 0) = v0;                                \
        *(float4*)LADDR(G, 1) = v1;                                \
        *(float4*)LADDR(G, 2) = v2;                                \
        *(float4*)LADDR(G, 3) = v3;
#define GUARD(G)                                                   \
        if ((G) >= NG) { while (cdone[dir] < (G) - NG) {} }        \
        asm volatile("" ::: "memory");
#define FLAG(G)                                                    \
        asm volatile("s_waitcnt lgkmcnt(0)" ::: "memory");         \
        pflag[dir][half][(G) & 7] = (G);

        PLOAD(a0, a1, a2, a3, 0)
        for (int g = 0; g < 32; g += 2) {
            // even g: set A holds group g; prefetch g+1 into B
            if (g + 1 <= 31) { PLOAD(b0, b1, b2, b3, g + 1) }
            if (g + 1 <= 31) asm volatile("s_waitcnt vmcnt(4)" ::: "memory");
            else             asm volatile("s_waitcnt vmcnt(0)" ::: "memory");
            GUARD(g)
            PWRITE(a0, a1, a2, a3, g)
            FLAG(g)
            // odd g+1: set B holds g+1; prefetch g+2 into A
            if (g + 2 <= 31) { PLOAD(a0, a1, a2, a3, g + 2) }
            if (g + 2 <= 31) asm volatile("s_waitcnt vmcnt(4)" ::: "memory");
            else             asm volatile("s_waitcnt vmcnt(0)" ::: "memory");
            GUARD(g + 1)
            PWRITE(b0, b1, b2, b3, g + 1)
            FLAG(g + 1)
        }
#undef GADDR
#undef LADDR
#undef PLOAD
#undef PWRITE
#undef GUARD
#undef FLAG
    } else {
        // ---------------- consumer (DP) waves ----------------
        const int lab  = y_true[b * Lc + lane];
        const int labp = __shfl_up(lab, 1);
        const int labn = __shfl_down(lab, 1);

        if (wid == 0) {
            // forward DP: steps/rows 0..255
            const bool allowF = (lane >= 1) && (lab != labp);
            auto stepF = [&](float pBf, float pLf) {
                const double pB = (double)pBf, pL = (double)pLf;
                const double prevHi = dpp_up1_d(0.0, hi);
                const double sk  = allowF ? prevHi : 0.0;
                const double nlo = (lo + prevHi) * pB;
                const double nhi = (hi + lo + sk) * pL;
                ex = (ex + hi) * pB;     // real only at lane 63 (127->128)
                hi = nhi; lo = nlo;
            };
            for (int g = 0; g < 32; ++g) {
                while (pflag[0][0][g & 7] < g || pflag[0][1][g & 7] < g) {}
                asm volatile("" ::: "memory");
                const int sb = (g & 7) * 8;
#define RDF(j) const float cL##j = ring[0][sb + j][lab] + EPSF, \
                           cB##j = ring[0][sb + j][Cc - 1] + EPSF;
                RDF(0) RDF(1) RDF(2) RDF(3) RDF(4) RDF(5) RDF(6) RDF(7)
#undef RDF
                if (g == 0) {
                    lo = (lane == 0) ? (double)cB0 : 0.0;    // alpha0(0)
                    hi = (lane == 0) ? (double)cL0 : 0.0;    // alpha0(1)
                } else stepF(cB0, cL0);
                stepF(cB1, cL1); stepF(cB2, cL2); stepF(cB3, cL3);
                stepF(cB4, cL4); stepF(cB5, cL5); stepF(cB6, cL6);
                stepF(cB7, cL7);
                asm volatile("s_waitcnt lgkmcnt(0)" ::: "memory");
                cdone[0] = g;
            }
        } else {
            // backward DP: local rows 0..255 <-> t = 511..256
            const bool allowB = (lane < 63) && (labn != lab);
            auto stepB = [&](float pBf, float pLf) {
                const double pB = (double)pBf, pL = (double)pLf;
                const double nlo_s = dpp_dn1_d(ex, lo);   // B(2l+2); l63 <- ex
                const double nhi_s = dpp_dn1_d(0.0, hi);  // B(2l+3); l63 <- 0
                const double sk = allowB ? nhi_s : 0.0;
                const double l2 = (lo + hi) * pB;
                const double h2 = (hi + nlo_s + sk) * pL;
                ex = ex * pB;
                lo = l2; hi = h2;
            };
            for (int g = 0; g < 32; ++g) {
                while (pflag[1][0][g & 7] < g || pflag[1][1][g & 7] < g) {}
                asm volatile("" ::: "memory");
                const int sb = (g & 7) * 8;
#define RDB(j) const float cL##j = ring[1][sb + j][lab] + EPSF, \
                           cB##j = ring[1][sb + j][Cc - 1] + EPSF;
                RDB(0) RDB(1) RDB(2) RDB(3) RDB(4) RDB(5) RDB(6) RDB(7)
#undef RDB
                if (g == 0) {
                    ex = (double)cB0;                          // beta511(128)
                    hi = (lane == 63) ? (double)cL0 : 0.0;     // beta511(127)
                    lo = 0.0;
                } else stepB(cB0, cL0);
                stepB(cB1, cL1); stepB(cB2, cL2); stepB(cB3, cL3);
                stepB(cB4, cL4); stepB(cB5, cL5); stepB(cB6, cL6);
                stepB(cB7, cL7);
                asm volatile("s_waitcnt lgkmcnt(0)" ::: "memory");
                cdone[1] = g;
            }
            // cut combine half-step: C(s) = B(s) + B(s+1) + allowB(s)*B(s+2),
            // stored log2-domain (R4 lesson: anti-aligned maxima).
            const double nlo_s = dpp_dn1_d(ex, lo);
            const double nhi_s = dpp_dn1_d(0.0, hi);
            const double sk = allowB ? nhi_s : 0.0;
            Cl[lane] = dlog2(lo + hi);
            Ch[lane] = dlog2(hi + nlo_s + sk);
            if (lane == 63) CexS = dlog2(ex);
        }
    }

    __syncthreads();

    if (wid == 0) {
        const float w1 = dlog2(lo) + Cl[lane];
        const float w2 = dlog2(hi) + Ch[lane];
        float w = lse2(w1, w2);
        if (lane == 63) w = lse2(w, dlog2(ex) + CexS);
        #pragma unroll
        for (int off = 32; off; off >>= 1) w = lse2(w, __shfl_xor(w, off));
        if (lane == 0)
            out[b] = -0.69314718055994530942f * w;     // ln2 * log2 -> ln
    }
}

extern "C" void kernel_launch(void* const* d_in, const int* in_sizes, int n_in,
                              void* d_out, int out_size, void* d_ws, size_t ws_size,
                              hipStream_t stream) {
    const int*   y_true = (const int*)d_in[0];
    const float* y_pred = (const float*)d_in[1];
    float*       out    = (float*)d_out;
    ctc_fb_kernel<<<dim3(Bc), dim3(384), 0, stream>>>(y_true, y_pred, out);
}